// Round 10
// baseline (477.187 us; speedup 1.0000x reference)
//
#include <hip/hip_runtime.h>
#include <cstdint>
#include <cstddef>

// ---------------- problem constants ----------------
#define DMODEL 1024
#define DINNER 2048
#define DSTATE 16
#define DCONV  4
#define DTRANK 64
#define BSZ    2
#define SEQL   2048
#define MROWS  (BSZ*SEQL)          // 4096
#define NCHUNK 32                  // scan chunks per sequence
#define CLEN   (SEQL/NCHUNK)       // 64

typedef __bf16 bf16;
typedef bf16  bf16x8 __attribute__((ext_vector_type(8)));
typedef bf16  bf16x4 __attribute__((ext_vector_type(4)));
typedef float floatx4 __attribute__((ext_vector_type(4)));

#define TLDC 129   // transposed-epilogue LDS leading dim (odd: column reads spread banks)

__device__ __forceinline__ float fsigmoid(float x){ return 1.f/(1.f+__expf(-x)); }
__device__ __forceinline__ float fsilu(float x){ return x*fsigmoid(x); }

__device__ __forceinline__ void gload_lds16(const void* g, void* l){
  __builtin_amdgcn_global_load_lds((__attribute__((address_space(1))) void*)g,
                                   (__attribute__((address_space(3))) void*)l,
                                   16, 0, 0);
}

// ---------------- prep: x cast (blocks 0..4095) + all 4 weight transposes ----------------
__global__ void k_prep(const float* __restrict__ x, bf16* __restrict__ xb,
                       const float* __restrict__ W_in, const float* __restrict__ W_out,
                       const float* __restrict__ W_xproj, const float* __restrict__ W_dt,
                       bf16* __restrict__ WinT, bf16* __restrict__ WoutT,
                       bf16* __restrict__ WxT, bf16* __restrict__ WdtT){
  __shared__ float tile[32][33];
  int b = blockIdx.x;
  if (b < 4096){                      // cast x -> bf16, vec4
    int i = (b*256 + threadIdx.x)*4;
    float4 v = *(const float4*)(x + i);
    bf16x4 o; o[0]=(bf16)v.x; o[1]=(bf16)v.y; o[2]=(bf16)v.z; o[3]=(bf16)v.w;
    *(bf16x4*)(xb + i) = o;
    return;
  }
  b -= 4096;
  const float* in; bf16* out; int R, C, outR, nbx;
  if      (b < 4096)            { in=W_in;    out=WinT;  R=1024; C=4096; outR=4096; nbx=128; }
  else if (b < 4096+2048)       { b-=4096;    in=W_out;  out=WoutT; R=2048; C=1024; outR=1024; nbx=32; }
  else if (b < 4096+2048+256)   { b-=6144;    in=W_xproj;out=WxT;  R=2048; C=96;   outR=128;  nbx=4; }
  else                          { b-=6400;    in=W_dt;   out=WdtT; R=64;   C=2048; outR=2048; nbx=64; }
  int c0 = (b % nbx)*32, r0 = (b / nbx)*32;
  int tx = threadIdx.x & 31, ty = threadIdx.x >> 5;
  #pragma unroll
  for (int ii=0; ii<4; ++ii){
    int r = r0 + ty + ii*8, c = c0 + tx;
    float v = 0.f;
    if (r < R && c < C) v = in[(size_t)r*C + c];
    tile[ty+ii*8][tx] = v;
  }
  __syncthreads();
  #pragma unroll
  for (int ii=0; ii<4; ++ii){
    int orow = c0 + ty + ii*8;   // original col
    int ocol = r0 + tx;          // original row
    if (orow < outR && ocol < R) out[(size_t)orow*R + ocol] = (bf16)tile[tx][ty+ii*8];
  }
}

// ---------------- bf16 MFMA GEMM: C = A(M,K) * B^T(N,K), 128x128 tile, BK=32 dbuf ------
// R7-proven K-loop (orientation A=activations: fast staging + store patterns).
// EPI 0: fp32 scattered dword stores to C0 + z*M*N (split-K partials)
// EPI 1: GEMM-in, TRANSPOSED outputs: col<DINNER -> u_preT bf16 (C1, [d][row]);
//        col>=DINNER -> silu -> resbT (C2, [d][row]). Tile->LDS->column-gather stores:
//        per instr a wave writes 4 cols x 256B contiguous (R9's 32x32B scatter was the
//        125us store stall).
// EPI 2: dt, TRANSPOSED: bf16(softplus(v + bias[bn+lcol])) -> dtT (C1, [d][row])
template<int EPI>
__global__ __launch_bounds__(256)
void k_gemm_bt(const bf16* __restrict__ A, const bf16* __restrict__ Bt,
               int M, int N, int K,
               float* __restrict__ C0, bf16* __restrict__ C1, bf16* __restrict__ C2,
               const float* __restrict__ bias){
  __shared__ bf16 lds[17408];            // K-loop: 4 x 4096-elem bufs; epilogue: 128 x 129
  const int tid  = threadIdx.x;
  const int lane = tid & 63;
  const int wave = tid >> 6;
  const int quad = lane >> 4;
  const int mrow = lane & 15;
  const int wr = wave >> 1, wc = wave & 1;
  const int bm = blockIdx.y * 128, bn = blockIdx.x * 128;
  const int Ks   = K / gridDim.z;
  const int kbeg = blockIdx.z * Ks;

  floatx4 acc[4][4];
  #pragma unroll
  for (int i=0;i<4;++i)
    #pragma unroll
    for (int j=0;j<4;++j) acc[i][j] = (floatx4){0.f,0.f,0.f,0.f};

  const int ar0 = tid >> 2;
  const int kc  = ((tid & 3) ^ ((ar0 >> 1) & 3)) * 8;
  const bf16* Ag0 = A  + (size_t)(bm + ar0)      * K + kc;
  const bf16* Ag1 = A  + (size_t)(bm + ar0 + 64) * K + kc;
  const bf16* Bg0 = Bt + (size_t)(bn + ar0)      * K + kc;
  const bf16* Bg1 = Bt + (size_t)(bn + ar0 + 64) * K + kc;
  const int ksl = (mrow >> 1) & 3;

  auto stage = [&](int k0, int p){
    bf16* bA = lds + p*4096;
    bf16* bB = lds + 8192 + p*4096;
    gload_lds16(Ag0 + k0, bA + (size_t)tid*8);
    gload_lds16(Ag1 + k0, bA + (size_t)(256+tid)*8);
    gload_lds16(Bg0 + k0, bB + (size_t)tid*8);
    gload_lds16(Bg1 + k0, bB + (size_t)(256+tid)*8);
  };

  stage(kbeg, 0);
  int p = 0;
  for (int k0 = kbeg; k0 < kbeg + Ks; k0 += 32){
    __syncthreads();
    if (k0 + 32 < kbeg + Ks) stage(k0 + 32, p ^ 1);
    const bf16* bA = lds + p*4096;
    const bf16* bB = lds + 8192 + p*4096;
    bf16x8 af[4], bfr[4];
    #pragma unroll
    for (int i=0;i<4;++i)
      af[i] = *(const bf16x8*)(bA + (wr*64 + i*16 + mrow)*32 + (quad ^ ksl)*8);
    #pragma unroll
    for (int j=0;j<4;++j)
      bfr[j] = *(const bf16x8*)(bB + (wc*64 + j*16 + mrow)*32 + (quad ^ ksl)*8);
    #pragma unroll
    for (int i=0;i<4;++i)
      #pragma unroll
      for (int j=0;j<4;++j)
        acc[i][j] = __builtin_amdgcn_mfma_f32_16x16x32_bf16(af[i], bfr[j], acc[i][j], 0,0,0);
    p ^= 1;
  }

  // ---- epilogue: lane holds D[row=quad*4+r][col=mrow] of each 16x16 tile ----
  if (EPI == 0){
    float* Cz = C0 + (size_t)blockIdx.z * M * N;
    #pragma unroll
    for (int i=0;i<4;++i){
      #pragma unroll
      for (int r=0;r<4;++r){
        int row = bm + wr*64 + i*16 + quad*4 + r;
        #pragma unroll
        for (int j=0;j<4;++j){
          int col = bn + wc*64 + j*16 + mrow;
          Cz[(size_t)row*N + col] = acc[i][j][r];
        }
      }
    }
  } else {
    __syncthreads();   // all waves done with K-loop LDS
    const bool isres = (EPI == 1) && (bn >= DINNER);
    #pragma unroll
    for (int i=0;i<4;++i)
      #pragma unroll
      for (int r=0;r<4;++r){
        int lrow = wr*64 + i*16 + quad*4 + r;
        #pragma unroll
        for (int j=0;j<4;++j){
          int lcol = wc*64 + j*16 + mrow;
          float v = acc[i][j][r];
          float vt;
          if (EPI == 1) vt = isres ? fsilu(v) : v;
          else {
            float z = v + bias[bn + lcol];
            vt = (z > 20.f) ? z : log1pf(__expf(z));
          }
          lds[lrow*TLDC + lcol] = (bf16)vt;
        }
      }
    __syncthreads();
    // transposed readout: out[col][row]; per instr: 4 cols x 256B contiguous per wave
    bf16* base;
    if (EPI == 1) base = isres ? (C2 + (size_t)(bn - DINNER)*MROWS) : (C1 + (size_t)bn*MROWS);
    else          base = C1 + (size_t)bn*MROWS;
    const int chunk = tid & 15;          // 8-row chunk within column
    const int c0 = tid >> 4;             // column base (0..15)
    #pragma unroll
    for (int s=0;s<8;++s){
      int col = c0 + s*16;
      bf16x8 vv;
      #pragma unroll
      for (int k=0;k<8;++k)
        vv[k] = lds[(chunk*8 + k)*TLDC + col];
      *(bf16x8*)(base + (size_t)col*MROWS + bm + chunk*8) = vv;
    }
  }
}

// ---------------- split-K reduce for x_dbl (+ fused dt_low bf16 slice cast) ----------------
__global__ void k_xdbl_reduce(const float* __restrict__ part, float* __restrict__ xdbl,
                              bf16* __restrict__ dtlowb){
  int t = blockIdx.x*blockDim.x + threadIdx.x;   // MROWS*128/4 threads
  int i4 = t*4;
  floatx4 acc = (floatx4){0.f,0.f,0.f,0.f};
  #pragma unroll
  for (int z=0; z<8; ++z)
    acc += *(const floatx4*)(part + (size_t)z*MROWS*128 + i4);
  *(floatx4*)(xdbl + i4) = acc;
  int r = i4 >> 7, c = i4 & 127;
  if (c < DTRANK){
    bf16x4 o; o[0]=(bf16)acc[0]; o[1]=(bf16)acc[1]; o[2]=(bf16)acc[2]; o[3]=(bf16)acc[3];
    *(bf16x4*)(dtlowb + (size_t)r*DTRANK + c) = o;
  }
}

// ---------------- split-K=2 reduce for out GEMM (fp32) ----------------
__global__ void k_out_reduce(const float* __restrict__ part, float* __restrict__ out){
  int i4 = (blockIdx.x*blockDim.x + threadIdx.x)*4;
  floatx4 a = *(const floatx4*)(part + i4);
  floatx4 b = *(const floatx4*)(part + (size_t)MROWS*DMODEL + i4);
  *(floatx4*)(out + i4) = a + b;
}

// ---------------- depthwise causal conv on transposed input, dual-layout output ----------
// Block = 64 rows x 64 d. Reads u_preT[d][.] contiguous; writes ubT[d][.] contiguous
// and plain ub[row][d] via XOR-swizzled LDS transpose (elem addr = dloc*64 + (c^dloc)).
__global__ void k_conv2(const bf16* __restrict__ upreT,
                        const float* __restrict__ conv_w, const float* __restrict__ conv_b,
                        bf16* __restrict__ ubT, bf16* __restrict__ ub){
  __shared__ bf16 tile[64*64];
  const int r0 = blockIdx.x * 64;
  const int d0 = blockIdx.y * 64;
  const int t  = threadIdx.x;
  const int dloc = t & 63, q = t >> 6;       // thread: one d, 16 rows
  const int d = d0 + dloc;
  const int s = r0 + q*16;
  const bf16* src = upreT + (size_t)d*MROWS + s;
  bf16x8 a0 = *(const bf16x8*)(src - 8);     // rows s-8..s-1 (halo; masked at seq start)
  bf16x8 a1 = *(const bf16x8*)(src);
  bf16x8 a2 = *(const bf16x8*)(src + 8);
  float v[24];
  #pragma unroll
  for (int j=0;j<8;++j){ v[j]=(float)a0[j]; v[8+j]=(float)a1[j]; v[16+j]=(float)a2[j]; }
  if ((s & (SEQL-1)) == 0){ v[5]=0.f; v[6]=0.f; v[7]=0.f; }   // sequence start: no left ctx
  float4 w = *(const float4*)(conv_w + d*4);
  float cb = conv_b[d];
  float o[16];
  #pragma unroll
  for (int i=0;i<16;++i)
    o[i] = fsilu(cb + w.x*v[i+5] + w.y*v[i+6] + w.z*v[i+7] + w.w*v[i+8]);
  bf16x8 o0, o1;
  #pragma unroll
  for (int j=0;j<8;++j){ o0[j]=(bf16)o[j]; o1[j]=(bf16)o[8+j]; }
  *(bf16x8*)(ubT + (size_t)d*MROWS + s)     = o0;
  *(bf16x8*)(ubT + (size_t)d*MROWS + s + 8) = o1;
  #pragma unroll
  for (int i=0;i<16;++i){
    int c = q*16 + i;
    tile[dloc*64 + (c ^ dloc)] = (bf16)o[i];
  }
  __syncthreads();
  const int rloc = t >> 2, seg = t & 3;
  bf16x8 p0, p1;
  #pragma unroll
  for (int i=0;i<8;++i){
    int dp0 = seg*16 + i, dp1 = seg*16 + 8 + i;
    p0[i] = tile[dp0*64 + (rloc ^ dp0)];
    p1[i] = tile[dp1*64 + (rloc ^ dp1)];
  }
  *(bf16x8*)(ub + (size_t)(r0 + rloc)*DINNER + d0 + seg*16)     = p0;
  *(bf16x8*)(ub + (size_t)(r0 + rloc)*DINNER + d0 + seg*16 + 8) = p1;
}

// ---------------- scan phase 1: 4 states/thread, vectorized transposed loads -------------
__global__ void k_scan_phase1(const bf16* __restrict__ dtT, const bf16* __restrict__ ubT,
                              const float* __restrict__ x_dbl, const float* __restrict__ A_log,
                              float* __restrict__ Pbuf, float* __restrict__ Sbuf){
  int t  = blockIdx.x*blockDim.x + threadIdx.x;   // BSZ*NCHUNK*DINNER*4 = 524288
  int g  = t & 3;
  int d  = (t >> 2) & (DINNER-1);
  int bc = t >> 13;
  int c  = bc & (NCHUNK-1);
  int b  = bc >> 5;
  floatx4 alog = *(const floatx4*)(A_log + d*DSTATE + g*4);
  float an[4];
  #pragma unroll
  for (int n=0;n<4;++n) an[n] = -__expf(alog[n]);
  float P[4] = {1.f,1.f,1.f,1.f}, S[4] = {0.f,0.f,0.f,0.f};
  int base_row = b*SEQL + c*CLEN;
  const bf16* dtp = dtT + (size_t)d*MROWS + base_row;
  const bf16* ubp = ubT + (size_t)d*MROWS + base_row;
  for (int s8=0; s8<CLEN; s8+=8){
    bf16x8 dt8 = *(const bf16x8*)(dtp + s8);
    bf16x8 ub8 = *(const bf16x8*)(ubp + s8);
    #pragma unroll
    for (int i=0;i<8;++i){
      size_t row = base_row + s8 + i;
      float dtv = (float)dt8[i];
      float du  = dtv * (float)ub8[i];
      floatx4 Bv = *(const floatx4*)(x_dbl + row*128 + DTRANK + g*4);
      #pragma unroll
      for (int n=0;n<4;++n){
        float e = __expf(dtv*an[n]);
        P[n] *= e;
        S[n]  = fmaf(S[n], e, du*Bv[n]);
      }
    }
  }
  size_t ob = ((size_t)bc*DINNER + d)*DSTATE + g*4;
  floatx4 Pv = {P[0],P[1],P[2],P[3]}, Sv = {S[0],S[1],S[2],S[3]};
  *(floatx4*)(Pbuf + ob) = Pv;
  *(floatx4*)(Sbuf + ob) = Sv;
}

// ---------------- scan phase 2: chunk combine over (b,d,n); Sbuf <- entry state ----------
__global__ void k_scan_phase2(const float* __restrict__ Pbuf, float* __restrict__ Sbuf){
  int t = blockIdx.x*blockDim.x + threadIdx.x;   // BSZ*DINNER*DSTATE = 65536
  int b   = t >> 15;
  int rem = t & 32767;           // d*16 + n
  float h = 0.f;
  for (int c=0;c<NCHUNK;++c){
    size_t ix = (size_t)(b*NCHUNK + c)*DINNER*DSTATE + rem;
    float p = Pbuf[ix], s = Sbuf[ix];
    Sbuf[ix] = h;                // entry state for chunk c
    h = fmaf(p, h, s);
  }
}

// ---------------- scan phase 3: replay with entry state; fuse +u*D, *silu(res) -----------
__global__ void k_scan_phase3(const bf16* __restrict__ dtT, const bf16* __restrict__ ubT,
                              const float* __restrict__ x_dbl, const float* __restrict__ A_log,
                              const float* __restrict__ Dvec, const float* __restrict__ Hin,
                              const bf16* __restrict__ resbT, bf16* __restrict__ yb){
  int t  = blockIdx.x*blockDim.x + threadIdx.x;
  int g  = t & 3;
  int d  = (t >> 2) & (DINNER-1);
  int bc = t >> 13;
  int c  = bc & (NCHUNK-1);
  int b  = bc >> 5;
  floatx4 alog = *(const floatx4*)(A_log + d*DSTATE + g*4);
  float an[4];
  #pragma unroll
  for (int n=0;n<4;++n) an[n] = -__expf(alog[n]);
  floatx4 h = *(const floatx4*)(Hin + ((size_t)bc*DINNER + d)*DSTATE + g*4);
  float Dd = Dvec[d];
  int base_row = b*SEQL + c*CLEN;
  const bf16* dtp = dtT   + (size_t)d*MROWS + base_row;
  const bf16* ubp = ubT   + (size_t)d*MROWS + base_row;
  const bf16* rsp = resbT + (size_t)d*MROWS + base_row;
  for (int s8=0; s8<CLEN; s8+=8){
    bf16x8 dt8 = *(const bf16x8*)(dtp + s8);
    bf16x8 ub8 = *(const bf16x8*)(ubp + s8);
    bf16x8 rs8 = *(const bf16x8*)(rsp + s8);
    #pragma unroll
    for (int i=0;i<8;++i){
      size_t row = base_row + s8 + i;
      float dtv = (float)dt8[i];
      float uv  = (float)ub8[i];
      float du  = dtv*uv;
      floatx4 Bv = *(const floatx4*)(x_dbl + row*128 + DTRANK + g*4);
      floatx4 Cv = *(const floatx4*)(x_dbl + row*128 + DTRANK + DSTATE + g*4);
      float y = 0.f;
      #pragma unroll
      for (int n=0;n<4;++n){
        float e = __expf(dtv*an[n]);
        h[n] = fmaf(h[n], e, du*Bv[n]);
        y = fmaf(h[n], Cv[n], y);
      }
      y += __shfl_xor(y, 1);
      y += __shfl_xor(y, 2);
      if (g == 0){
        y = (y + uv*Dd) * (float)rs8[i];
        yb[row*DINNER + d] = (bf16)y;
      }
    }
  }
}

// ---------------- host side ----------------
extern "C" void kernel_launch(void* const* d_in, const int* in_sizes, int n_in,
                              void* d_out, int out_size, void* d_ws, size_t ws_size,
                              hipStream_t stream){
  const float* x      = (const float*)d_in[0];
  const float* W_in   = (const float*)d_in[1];
  const float* conv_w = (const float*)d_in[2];
  const float* conv_b = (const float*)d_in[3];
  const float* W_xproj= (const float*)d_in[4];
  const float* W_dt   = (const float*)d_in[5];
  const float* b_dt   = (const float*)d_in[6];
  const float* A_log  = (const float*)d_in[7];
  const float* Dv     = (const float*)d_in[8];
  const float* W_out  = (const float*)d_in[9];
  float* out = (float*)d_out;

  uint8_t* wp = (uint8_t*)d_ws;
  auto alloc = [&](size_t bytes)->void*{ void* p = wp; wp += (bytes + 255) & ~(size_t)255; return p; };
  bf16*  xb     = (bf16*) alloc((size_t)MROWS*DMODEL*2);
  bf16*  WinT   = (bf16*) alloc((size_t)2*DINNER*DMODEL*2);   // (4096,1024)
  bf16*  WoutT  = (bf16*) alloc((size_t)DMODEL*DINNER*2);     // (1024,2048)
  bf16*  WxT    = (bf16*) alloc((size_t)128*DINNER*2);        // (128,2048) padded
  bf16*  WdtT   = (bf16*) alloc((size_t)DINNER*DTRANK*2);     // (2048,64)
  // updtT (16MB: u_preT, then dtT; [d][row]) + scanPS (16MB) contiguous; the 32MB span is
  // reused as GEMM-out split-K=2 partials after scan phase3 (both dead by then).
  bf16*  updtT  = (bf16*) alloc((size_t)MROWS*DINNER*2);      // [d][row]
  float* scanPS = (float*)alloc((size_t)2*BSZ*NCHUNK*DSTATE*DINNER*4);  // 16MB
  float* Pbuf   = scanPS;
  float* Sbuf   = scanPS + (size_t)BSZ*NCHUNK*DSTATE*DINNER;
  float* xdbl_part = scanPS;                                  // 8 z-slices * 2 MB
  float* outpart   = (float*)updtT;                           // 2 z-slices * 16 MB
  bf16*  resbT  = (bf16*) alloc((size_t)MROWS*DINNER*2);      // silu(res), [d][row]
  bf16*  ubT    = (bf16*) alloc((size_t)MROWS*DINNER*2);      // conv out, [d][row]
  bf16*  ub     = (bf16*) alloc((size_t)MROWS*DINNER*2);      // conv out, [row][d]
  float* xdbl   = (float*)alloc((size_t)MROWS*128*4);         // padded ld=128
  bf16*  dtlowb = (bf16*) alloc((size_t)MROWS*DTRANK*2);
  bf16*  yb     = (bf16*) alloc((size_t)MROWS*DINNER*2);

  // prep: cast x + all weight transposes, one launch
  k_prep<<<4096 + 4096+2048+256+128, 256, 0, stream>>>(x, xb, W_in, W_out, W_xproj, W_dt,
                                                       WinT, WoutT, WxT, WdtT);

  // GEMM-in (R8 orientation, transposed epilogue): -> u_preT + resbT ([d][row])
  k_gemm_bt<1><<<dim3(4096/128, 4096/128), 256, 0, stream>>>(xb, WinT, MROWS, 2*DINNER, DMODEL, nullptr, updtT, resbT, nullptr);
  // depthwise conv + silu: u_preT -> ubT (contiguous) + ub (plain, via LDS transpose)
  k_conv2<<<dim3(MROWS/64, DINNER/64), 256, 0, stream>>>(updtT, conv_w, conv_b, ubT, ub);
  // x_dbl = u @ W_xproj  (N padded to 128), split-K=8 -> partials -> reduce (+dt_low cast)
  k_gemm_bt<0><<<dim3(1, 4096/128, 8), 256, 0, stream>>>(ub, WxT, MROWS, 128, DINNER, xdbl_part, nullptr, nullptr, nullptr);
  k_xdbl_reduce<<<(MROWS*128/4)/256, 256, 0, stream>>>(xdbl_part, xdbl, dtlowb);
  // dt (R8 orientation, transposed epilogue): softplus(dt_low @ W_dt + b_dt) -> dtT ([d][row])
  k_gemm_bt<2><<<dim3(2048/128, 4096/128), 256, 0, stream>>>(dtlowb, WdtT, MROWS, DINNER, DTRANK, nullptr, updtT, nullptr, b_dt);
  // chunked selective scan (4 states/thread, vectorized transposed loads)
  k_scan_phase1<<<BSZ*NCHUNK*DINNER*4/256, 256, 0, stream>>>(updtT, ubT, xdbl, A_log, Pbuf, Sbuf);
  k_scan_phase2<<<BSZ*DINNER*DSTATE/256, 256, 0, stream>>>(Pbuf, Sbuf);
  k_scan_phase3<<<BSZ*NCHUNK*DINNER*4/256, 256, 0, stream>>>(updtT, ubT, xdbl, A_log, Dv, Sbuf, resbT, yb);
  // out = y @ W_out, split-K=2 (partials overwrite dead updtT+scanPS span) -> reduce
  k_gemm_bt<0><<<dim3(1024/128, 4096/128, 2), 256, 0, stream>>>(yb, WoutT, MROWS, DMODEL, DINNER, outpart, nullptr, nullptr, nullptr);
  k_out_reduce<<<(MROWS*DMODEL/4)/256, 256, 0, stream>>>(outpart, out);
}

// Round 11
// 363.816 us; speedup vs baseline: 1.3116x; 1.3116x over previous
//
#include <hip/hip_runtime.h>
#include <cstdint>
#include <cstddef>

// ---------------- problem constants ----------------
#define DMODEL 1024
#define DINNER 2048
#define DSTATE 16
#define DCONV  4
#define DTRANK 64
#define BSZ    2
#define SEQL   2048
#define MROWS  (BSZ*SEQL)          // 4096
#define NCHUNK 32                  // scan chunks per sequence
#define CLEN   (SEQL/NCHUNK)       // 64

typedef __bf16 bf16;
typedef bf16  bf16x8 __attribute__((ext_vector_type(8)));
typedef bf16  bf16x4 __attribute__((ext_vector_type(4)));
typedef float floatx4 __attribute__((ext_vector_type(4)));

#define EPILDC 136   // padded epilogue LDS leading dim (272B = 4 mod 32 banks)
#define SLDC   72    // scan tile LDS leading dim (rotates start bank by 4/row)

__device__ __forceinline__ float fsigmoid(float x){ return 1.f/(1.f+__expf(-x)); }
__device__ __forceinline__ float fsilu(float x){ return x*fsigmoid(x); }

__device__ __forceinline__ void gload_lds16(const void* g, void* l){
  __builtin_amdgcn_global_load_lds((__attribute__((address_space(1))) void*)g,
                                   (__attribute__((address_space(3))) void*)l,
                                   16, 0, 0);
}

// ---------------- prep: x cast (blocks 0..4095) + all 4 weight transposes ----------------
__global__ void k_prep(const float* __restrict__ x, bf16* __restrict__ xb,
                       const float* __restrict__ W_in, const float* __restrict__ W_out,
                       const float* __restrict__ W_xproj, const float* __restrict__ W_dt,
                       bf16* __restrict__ WinT, bf16* __restrict__ WoutT,
                       bf16* __restrict__ WxT, bf16* __restrict__ WdtT){
  __shared__ float tile[32][33];
  int b = blockIdx.x;
  if (b < 4096){                      // cast x -> bf16, vec4
    int i = (b*256 + threadIdx.x)*4;
    float4 v = *(const float4*)(x + i);
    bf16x4 o; o[0]=(bf16)v.x; o[1]=(bf16)v.y; o[2]=(bf16)v.z; o[3]=(bf16)v.w;
    *(bf16x4*)(xb + i) = o;
    return;
  }
  b -= 4096;
  const float* in; bf16* out; int R, C, outR, nbx;
  if      (b < 4096)            { in=W_in;    out=WinT;  R=1024; C=4096; outR=4096; nbx=128; }
  else if (b < 4096+2048)       { b-=4096;    in=W_out;  out=WoutT; R=2048; C=1024; outR=1024; nbx=32; }
  else if (b < 4096+2048+256)   { b-=6144;    in=W_xproj;out=WxT;  R=2048; C=96;   outR=128;  nbx=4; }
  else                          { b-=6400;    in=W_dt;   out=WdtT; R=64;   C=2048; outR=2048; nbx=64; }
  int c0 = (b % nbx)*32, r0 = (b / nbx)*32;
  int tx = threadIdx.x & 31, ty = threadIdx.x >> 5;
  #pragma unroll
  for (int ii=0; ii<4; ++ii){
    int r = r0 + ty + ii*8, c = c0 + tx;
    float v = 0.f;
    if (r < R && c < C) v = in[(size_t)r*C + c];
    tile[ty+ii*8][tx] = v;
  }
  __syncthreads();
  #pragma unroll
  for (int ii=0; ii<4; ++ii){
    int orow = c0 + ty + ii*8;   // original col
    int ocol = r0 + tx;          // original row
    if (orow < outR && ocol < R) out[(size_t)orow*R + ocol] = (bf16)tile[tx][ty+ii*8];
  }
}

// ---------------- bf16 MFMA GEMM: C = A(M,K) * B^T(N,K), 128x128 tile, BK=32 dbuf ------
// R7-proven: single-barrier double-buffered K-loop, 0-conflict swizzle, [row][d] outputs.
// EPI 0: fp32 scattered dword stores to C0 + z*M*N (split-K partials)
// EPI 1: GEMM-in: col<DINNER -> u_pre bf16 (C1); col>=DINNER -> silu -> resb (C2)
// EPI 2: dt: bf16(softplus(acc + bias[col])) -> C1, ldc=N
template<int EPI>
__global__ __launch_bounds__(256)
void k_gemm_bt(const bf16* __restrict__ A, const bf16* __restrict__ Bt,
               int M, int N, int K,
               float* __restrict__ C0, bf16* __restrict__ C1, bf16* __restrict__ C2,
               const float* __restrict__ bias){
  __shared__ bf16 lds[17408];            // 34816B: K-loop 4x4096-elem bufs / epilogue 128x136
  const int tid  = threadIdx.x;
  const int lane = tid & 63;
  const int wave = tid >> 6;
  const int quad = lane >> 4;
  const int mrow = lane & 15;
  const int wr = wave >> 1, wc = wave & 1;
  const int bm = blockIdx.y * 128, bn = blockIdx.x * 128;
  const int Ks   = K / gridDim.z;
  const int kbeg = blockIdx.z * Ks;

  floatx4 acc[4][4];
  #pragma unroll
  for (int i=0;i<4;++i)
    #pragma unroll
    for (int j=0;j<4;++j) acc[i][j] = (floatx4){0.f,0.f,0.f,0.f};

  const int ar0 = tid >> 2;
  const int kc  = ((tid & 3) ^ ((ar0 >> 1) & 3)) * 8;
  const bf16* Ag0 = A  + (size_t)(bm + ar0)      * K + kc;
  const bf16* Ag1 = A  + (size_t)(bm + ar0 + 64) * K + kc;
  const bf16* Bg0 = Bt + (size_t)(bn + ar0)      * K + kc;
  const bf16* Bg1 = Bt + (size_t)(bn + ar0 + 64) * K + kc;
  const int ksl = (mrow >> 1) & 3;

  auto stage = [&](int k0, int p){
    bf16* bA = lds + p*4096;
    bf16* bB = lds + 8192 + p*4096;
    gload_lds16(Ag0 + k0, bA + (size_t)tid*8);
    gload_lds16(Ag1 + k0, bA + (size_t)(256+tid)*8);
    gload_lds16(Bg0 + k0, bB + (size_t)tid*8);
    gload_lds16(Bg1 + k0, bB + (size_t)(256+tid)*8);
  };

  stage(kbeg, 0);
  int p = 0;
  for (int k0 = kbeg; k0 < kbeg + Ks; k0 += 32){
    __syncthreads();
    if (k0 + 32 < kbeg + Ks) stage(k0 + 32, p ^ 1);
    const bf16* bA = lds + p*4096;
    const bf16* bB = lds + 8192 + p*4096;
    bf16x8 af[4], bfr[4];
    #pragma unroll
    for (int i=0;i<4;++i)
      af[i] = *(const bf16x8*)(bA + (wr*64 + i*16 + mrow)*32 + (quad ^ ksl)*8);
    #pragma unroll
    for (int j=0;j<4;++j)
      bfr[j] = *(const bf16x8*)(bB + (wc*64 + j*16 + mrow)*32 + (quad ^ ksl)*8);
    #pragma unroll
    for (int i=0;i<4;++i)
      #pragma unroll
      for (int j=0;j<4;++j)
        acc[i][j] = __builtin_amdgcn_mfma_f32_16x16x32_bf16(af[i], bfr[j], acc[i][j], 0,0,0);
    p ^= 1;
  }

  // ---- epilogue: lane holds D[row=quad*4+r][col=mrow] of each 16x16 tile ----
  if (EPI == 0){
    float* Cz = C0 + (size_t)blockIdx.z * M * N;
    #pragma unroll
    for (int i=0;i<4;++i){
      #pragma unroll
      for (int r=0;r<4;++r){
        int row = bm + wr*64 + i*16 + quad*4 + r;
        #pragma unroll
        for (int j=0;j<4;++j){
          int col = bn + wc*64 + j*16 + mrow;
          Cz[(size_t)row*N + col] = acc[i][j][r];
        }
      }
    }
  } else {
    __syncthreads();   // all waves done with K-loop LDS before overwrite
    const bool isres = (EPI == 1) && (bn >= DINNER);
    #pragma unroll
    for (int i=0;i<4;++i)
      #pragma unroll
      for (int r=0;r<4;++r){
        int lrow = wr*64 + i*16 + quad*4 + r;
        #pragma unroll
        for (int j=0;j<4;++j){
          int lcol = wc*64 + j*16 + mrow;
          float v = acc[i][j][r];
          float vt;
          if (EPI == 1) vt = isres ? fsilu(v) : v;
          else {
            float z = v + bias[bn + lcol];
            vt = (z > 20.f) ? z : log1pf(__expf(z));
          }
          lds[lrow*EPILDC + lcol] = (bf16)vt;
        }
      }
    __syncthreads();
    bf16* dst; int ldc;
    if (EPI == 1){ ldc = DINNER; dst = isres ? (C2 + (bn - DINNER)) : (C1 + bn); }
    else         { ldc = N;      dst = C1 + bn; }
    const int rr = tid >> 1, hh = (tid & 1)*64;
    #pragma unroll
    for (int i=0;i<8;++i)
      *(bf16x8*)(dst + (size_t)(bm + rr)*ldc + hh + i*8) =
        *(const bf16x8*)(lds + rr*EPILDC + hh + i*8);
  }
}

// ---------------- split-K reduce for x_dbl (+ fused dt_low bf16 slice cast) ----------------
__global__ void k_xdbl_reduce(const float* __restrict__ part, float* __restrict__ xdbl,
                              bf16* __restrict__ dtlowb){
  int t = blockIdx.x*blockDim.x + threadIdx.x;   // MROWS*128/4 threads
  int i4 = t*4;
  floatx4 acc = (floatx4){0.f,0.f,0.f,0.f};
  #pragma unroll
  for (int z=0; z<8; ++z)
    acc += *(const floatx4*)(part + (size_t)z*MROWS*128 + i4);
  *(floatx4*)(xdbl + i4) = acc;
  int r = i4 >> 7, c = i4 & 127;
  if (c < DTRANK){
    bf16x4 o; o[0]=(bf16)acc[0]; o[1]=(bf16)acc[1]; o[2]=(bf16)acc[2]; o[3]=(bf16)acc[3];
    *(bf16x4*)(dtlowb + (size_t)r*DTRANK + c) = o;
  }
}

// ---------------- split-K=2 reduce for out GEMM (fp32) ----------------
__global__ void k_out_reduce(const float* __restrict__ part, float* __restrict__ out){
  int i4 = (blockIdx.x*blockDim.x + threadIdx.x)*4;
  floatx4 a = *(const floatx4*)(part + i4);
  floatx4 b = *(const floatx4*)(part + (size_t)MROWS*DMODEL + i4);
  *(floatx4*)(out + i4) = a + b;
}

// ---------------- depthwise causal conv (width 4) + bias + SiLU -> bf16, vec4 in d ------
__global__ void k_conv_silu(const bf16* __restrict__ u_pre,
                            const float* __restrict__ conv_w,
                            const float* __restrict__ conv_b,
                            bf16* __restrict__ ub){
  int t   = blockIdx.x*blockDim.x + threadIdx.x;   // MROWS*DINNER/4
  int d4  = (t & (DINNER/4-1))*4;
  int row = t >> 9;
  int l   = row & (SEQL-1);
  float4 cb = *(const float4*)(conv_b + d4);
  float acc[4] = {cb.x, cb.y, cb.z, cb.w};
  float4 w0 = *(const float4*)(conv_w + (d4+0)*4);
  float4 w1 = *(const float4*)(conv_w + (d4+1)*4);
  float4 w2 = *(const float4*)(conv_w + (d4+2)*4);
  float4 w3 = *(const float4*)(conv_w + (d4+3)*4);
  float wk[4][4] = {{w0.x,w0.y,w0.z,w0.w},{w1.x,w1.y,w1.z,w1.w},
                    {w2.x,w2.y,w2.z,w2.w},{w3.x,w3.y,w3.z,w3.w}};
  #pragma unroll
  for (int k=0;k<4;++k){
    int lk = l + k - 3;
    if (lk >= 0){
      bf16x4 uv = *(const bf16x4*)(u_pre + (size_t)(row + k - 3)*DINNER + d4);
      #pragma unroll
      for (int j=0;j<4;++j) acc[j] += (float)uv[j] * wk[j][k];
    }
  }
  bf16x4 o;
  #pragma unroll
  for (int j=0;j<4;++j) o[j] = (bf16)fsilu(acc[j]);
  *(bf16x4*)(ub + (size_t)row*DINNER + d4) = o;
}

// ---------------- scan phase 1: LDS-staged tiles, 4 states/thread ------------------------
// Block covers one (b,c) chunk x 64 d's. Stage dt/ub 64x64 bf16 tiles via coalesced
// 128B-per-row vector loads; loop reads LDS scalars (dword-broadcast, conflict-free).
__global__ void k_scan_phase1(const bf16* __restrict__ dt, const bf16* __restrict__ ub,
                              const float* __restrict__ x_dbl, const float* __restrict__ A_log,
                              float* __restrict__ Pbuf, float* __restrict__ Sbuf){
  __shared__ bf16 sdt[64*SLDC], sub[64*SLDC];
  const int tid = threadIdx.x;
  int t  = blockIdx.x*256 + tid;
  int g  = t & 3;
  int d  = (t >> 2) & (DINNER-1);
  int dloc = d & 63, d0 = d & ~63;
  int bc = t >> 13;
  int c  = bc & (NCHUNK-1);
  int b  = bc >> 5;
  int base_row = b*SEQL + c*CLEN;
  {
    int r = tid >> 2, ch = (tid & 3)*16;
    const bf16* gd = dt + (size_t)(base_row + r)*DINNER + d0 + ch;
    const bf16* gu = ub + (size_t)(base_row + r)*DINNER + d0 + ch;
    *(bf16x8*)(sdt + r*SLDC + ch)     = *(const bf16x8*)(gd);
    *(bf16x8*)(sdt + r*SLDC + ch + 8) = *(const bf16x8*)(gd + 8);
    *(bf16x8*)(sub + r*SLDC + ch)     = *(const bf16x8*)(gu);
    *(bf16x8*)(sub + r*SLDC + ch + 8) = *(const bf16x8*)(gu + 8);
  }
  floatx4 alog = *(const floatx4*)(A_log + d*DSTATE + g*4);
  float an[4];
  #pragma unroll
  for (int n=0;n<4;++n) an[n] = -__expf(alog[n]);
  __syncthreads();
  float P[4] = {1.f,1.f,1.f,1.f}, S[4] = {0.f,0.f,0.f,0.f};
  #pragma unroll 8
  for (int s=0; s<CLEN; ++s){
    float dtv = (float)sdt[s*SLDC + dloc];
    float du  = dtv * (float)sub[s*SLDC + dloc];
    size_t row = base_row + s;
    floatx4 Bv = *(const floatx4*)(x_dbl + row*128 + DTRANK + g*4);
    #pragma unroll
    for (int n=0;n<4;++n){
      float e = __expf(dtv*an[n]);
      P[n] *= e;
      S[n]  = fmaf(S[n], e, du*Bv[n]);
    }
  }
  size_t ob = ((size_t)bc*DINNER + d)*DSTATE + g*4;
  floatx4 Pv = {P[0],P[1],P[2],P[3]}, Sv = {S[0],S[1],S[2],S[3]};
  *(floatx4*)(Pbuf + ob) = Pv;
  *(floatx4*)(Sbuf + ob) = Sv;
}

// ---------------- scan phase 2: chunk combine over (b,d,n); Sbuf <- entry state ----------
__global__ void k_scan_phase2(const float* __restrict__ Pbuf, float* __restrict__ Sbuf){
  int t = blockIdx.x*blockDim.x + threadIdx.x;   // BSZ*DINNER*DSTATE = 65536
  int b   = t >> 15;
  int rem = t & 32767;           // d*16 + n
  float h = 0.f;
  for (int c=0;c<NCHUNK;++c){
    size_t ix = (size_t)(b*NCHUNK + c)*DINNER*DSTATE + rem;
    float p = Pbuf[ix], s = Sbuf[ix];
    Sbuf[ix] = h;                // entry state for chunk c
    h = fmaf(p, h, s);
  }
}

// ---------------- scan phase 3: LDS-staged replay; fuse +u*D, *silu(res) -----------------
__global__ void k_scan_phase3(const bf16* __restrict__ dt, const bf16* __restrict__ ub,
                              const float* __restrict__ x_dbl, const float* __restrict__ A_log,
                              const float* __restrict__ Dvec, const float* __restrict__ Hin,
                              const bf16* __restrict__ resb, bf16* __restrict__ yb){
  __shared__ bf16 sdt[64*SLDC], sub[64*SLDC], srs[64*SLDC];
  const int tid = threadIdx.x;
  int t  = blockIdx.x*256 + tid;
  int g  = t & 3;
  int d  = (t >> 2) & (DINNER-1);
  int dloc = d & 63, d0 = d & ~63;
  int bc = t >> 13;
  int c  = bc & (NCHUNK-1);
  int b  = bc >> 5;
  int base_row = b*SEQL + c*CLEN;
  {
    int r = tid >> 2, ch = (tid & 3)*16;
    const bf16* gd = dt   + (size_t)(base_row + r)*DINNER + d0 + ch;
    const bf16* gu = ub   + (size_t)(base_row + r)*DINNER + d0 + ch;
    const bf16* gr = resb + (size_t)(base_row + r)*DINNER + d0 + ch;
    *(bf16x8*)(sdt + r*SLDC + ch)     = *(const bf16x8*)(gd);
    *(bf16x8*)(sdt + r*SLDC + ch + 8) = *(const bf16x8*)(gd + 8);
    *(bf16x8*)(sub + r*SLDC + ch)     = *(const bf16x8*)(gu);
    *(bf16x8*)(sub + r*SLDC + ch + 8) = *(const bf16x8*)(gu + 8);
    *(bf16x8*)(srs + r*SLDC + ch)     = *(const bf16x8*)(gr);
    *(bf16x8*)(srs + r*SLDC + ch + 8) = *(const bf16x8*)(gr + 8);
  }
  floatx4 alog = *(const floatx4*)(A_log + d*DSTATE + g*4);
  float an[4];
  #pragma unroll
  for (int n=0;n<4;++n) an[n] = -__expf(alog[n]);
  floatx4 h = *(const floatx4*)(Hin + ((size_t)bc*DINNER + d)*DSTATE + g*4);
  float Dd = Dvec[d];
  __syncthreads();
  #pragma unroll 8
  for (int s=0; s<CLEN; ++s){
    float dtv = (float)sdt[s*SLDC + dloc];
    float uv  = (float)sub[s*SLDC + dloc];
    float du  = dtv*uv;
    size_t row = base_row + s;
    floatx4 Bv = *(const floatx4*)(x_dbl + row*128 + DTRANK + g*4);
    floatx4 Cv = *(const floatx4*)(x_dbl + row*128 + DTRANK + DSTATE + g*4);
    float y = 0.f;
    #pragma unroll
    for (int n=0;n<4;++n){
      float e = __expf(dtv*an[n]);
      h[n] = fmaf(h[n], e, du*Bv[n]);
      y = fmaf(h[n], Cv[n], y);
    }
    y += __shfl_xor(y, 1);
    y += __shfl_xor(y, 2);
    if (g == 0){
      y = (y + uv*Dd) * (float)srs[s*SLDC + dloc];
      yb[row*DINNER + d] = (bf16)y;
    }
  }
}

// ---------------- host side ----------------
extern "C" void kernel_launch(void* const* d_in, const int* in_sizes, int n_in,
                              void* d_out, int out_size, void* d_ws, size_t ws_size,
                              hipStream_t stream){
  const float* x      = (const float*)d_in[0];
  const float* W_in   = (const float*)d_in[1];
  const float* conv_w = (const float*)d_in[2];
  const float* conv_b = (const float*)d_in[3];
  const float* W_xproj= (const float*)d_in[4];
  const float* W_dt   = (const float*)d_in[5];
  const float* b_dt   = (const float*)d_in[6];
  const float* A_log  = (const float*)d_in[7];
  const float* Dv     = (const float*)d_in[8];
  const float* W_out  = (const float*)d_in[9];
  float* out = (float*)d_out;

  uint8_t* wp = (uint8_t*)d_ws;
  auto alloc = [&](size_t bytes)->void*{ void* p = wp; wp += (bytes + 255) & ~(size_t)255; return p; };
  bf16*  xb     = (bf16*) alloc((size_t)MROWS*DMODEL*2);
  bf16*  WinT   = (bf16*) alloc((size_t)2*DINNER*DMODEL*2);   // (4096,1024)
  bf16*  WoutT  = (bf16*) alloc((size_t)DMODEL*DINNER*2);     // (1024,2048)
  bf16*  WxT    = (bf16*) alloc((size_t)128*DINNER*2);        // (128,2048) padded
  bf16*  WdtT   = (bf16*) alloc((size_t)DINNER*DTRANK*2);     // (2048,64)
  // updt (16MB) + scanPS (16MB) contiguous; 32MB span reused as GEMM-out split-K=2
  // partials after scan phase3 (both dead by then).
  bf16*  updt   = (bf16*) alloc((size_t)MROWS*DINNER*2);      // u_pre bf16, then dt bf16
  float* scanPS = (float*)alloc((size_t)2*BSZ*NCHUNK*DSTATE*DINNER*4);  // 16MB
  float* Pbuf   = scanPS;
  float* Sbuf   = scanPS + (size_t)BSZ*NCHUNK*DSTATE*DINNER;
  float* xdbl_part = scanPS;                                  // 8 z-slices * 2 MB
  float* outpart   = (float*)updt;                            // 2 z-slices * 16 MB
  bf16*  resb   = (bf16*) alloc((size_t)MROWS*DINNER*2);      // silu(res)
  bf16*  ub     = (bf16*) alloc((size_t)MROWS*DINNER*2);      // conv+silu output
  float* xdbl   = (float*)alloc((size_t)MROWS*128*4);         // padded ld=128
  bf16*  dtlowb = (bf16*) alloc((size_t)MROWS*DTRANK*2);
  bf16*  yb     = (bf16*) alloc((size_t)MROWS*DINNER*2);

  // prep: cast x + all weight transposes, one launch
  k_prep<<<4096 + 4096+2048+256+128, 256, 0, stream>>>(x, xb, W_in, W_out, W_xproj, W_dt,
                                                       WinT, WoutT, WxT, WdtT);

  // GEMM-in: xr = x @ W_in, split epilogue -> u_pre (bf16) + silu(res) (bf16)
  k_gemm_bt<1><<<dim3(4096/128, 4096/128), 256, 0, stream>>>(xb, WinT, MROWS, 2*DINNER, DMODEL, nullptr, updt, resb, nullptr);
  // depthwise conv + silu -> ub (bf16)
  k_conv_silu<<<MROWS*DINNER/4/256, 256, 0, stream>>>(updt, conv_w, conv_b, ub);
  // x_dbl = u @ W_xproj  (N padded to 128), split-K=8 -> partials -> reduce (+dt_low cast)
  k_gemm_bt<0><<<dim3(1, 4096/128, 8), 256, 0, stream>>>(ub, WxT, MROWS, 128, DINNER, xdbl_part, nullptr, nullptr, nullptr);
  k_xdbl_reduce<<<(MROWS*128/4)/256, 256, 0, stream>>>(xdbl_part, xdbl, dtlowb);
  // dt = softplus(dt_low @ W_dt + b_dt) -> bf16 (overwrites u_pre buffer)
  k_gemm_bt<2><<<dim3(2048/128, 4096/128), 256, 0, stream>>>(dtlowb, WdtT, MROWS, DINNER, DTRANK, nullptr, updt, nullptr, b_dt);
  // chunked selective scan (4 states/thread, LDS-staged tiles)
  k_scan_phase1<<<BSZ*NCHUNK*DINNER*4/256, 256, 0, stream>>>(updt, ub, xdbl, A_log, Pbuf, Sbuf);
  k_scan_phase2<<<BSZ*DINNER*DSTATE/256, 256, 0, stream>>>(Pbuf, Sbuf);
  k_scan_phase3<<<BSZ*NCHUNK*DINNER*4/256, 256, 0, stream>>>(updt, ub, xdbl, A_log, Dv, Sbuf, resb, yb);
  // out = y @ W_out, split-K=2 (partials overwrite dead updt+scanPS span) -> reduce
  k_gemm_bt<0><<<dim3(1024/128, 4096/128, 2), 256, 0, stream>>>(yb, WoutT, MROWS, DMODEL, DINNER, outpart, nullptr, nullptr, nullptr);
  k_out_reduce<<<(MROWS*DMODEL/4)/256, 256, 0, stream>>>(outpart, out);
}